// Round 6
// baseline (459.422 us; speedup 1.0000x reference)
//
#include <hip/hip_runtime.h>

typedef unsigned short u16;
typedef __bf16 bf16x8 __attribute__((ext_vector_type(8)));
typedef float f32x4 __attribute__((ext_vector_type(4)));

#define NB 2
#define SS 2048
#define DM 1024
#define NH 16
#define DH 64
#define DFF 4096

__device__ __forceinline__ u16 f2bf(float f) {
    unsigned u = __float_as_uint(f);
    u += 0x7fff + ((u >> 16) & 1);   // RNE
    return (u16)(u >> 16);
}
__device__ __forceinline__ float bf2f(u16 h) {
    return __uint_as_float(((unsigned)h) << 16);
}
// async global->LDS, 16B per lane. LDS dest must be wave-uniform base + lane*16.
__device__ __forceinline__ void gld_lds16(const void* g, void* l) {
    __builtin_amdgcn_global_load_lds(
        (const __attribute__((address_space(1))) unsigned int*)(size_t)g,
        (__attribute__((address_space(3))) unsigned int*)(unsigned)(size_t)l,
        16, 0, 0);
}
__device__ __forceinline__ float gelu_f(float x) {
    return 0.5f * x * (1.f + erff(x * 0.70710678118654752f));
}

// ---------------- weight convert + transpose: w[K][N] fp32 -> wt[N][K] bf16 ----
__global__ void wtrans_kernel(const float* __restrict__ w, u16* __restrict__ wt,
                              int K, int N) {
    __shared__ unsigned tl[64][65];
    int n0 = blockIdx.x * 64, k0 = blockIdx.y * 64, t = threadIdx.x;
    for (int it = 0; it < 16; ++it) {
        int e = it * 256 + t; int r = e >> 6, c = e & 63;       // r: k, c: n
        tl[r][c] = f2bf(w[(size_t)(k0 + r) * N + n0 + c]);
    }
    __syncthreads();
    for (int it = 0; it < 16; ++it) {
        int e = it * 256 + t; int r = e >> 6, c = e & 63;       // r: n, c: k
        wt[(size_t)(n0 + r) * K + k0 + c] = (u16)tl[c][r];
    }
}

// batched version for the four 1024x1024 projection weights
__global__ void wtrans4_kernel(const float* __restrict__ a, const float* __restrict__ b,
                               const float* __restrict__ c, const float* __restrict__ d,
                               u16* __restrict__ oa, u16* __restrict__ ob,
                               u16* __restrict__ oc, u16* __restrict__ od) {
    __shared__ unsigned tl[64][65];
    const float* w; u16* wt;
    switch (blockIdx.z) {
        case 0: w = a; wt = oa; break;
        case 1: w = b; wt = ob; break;
        case 2: w = c; wt = oc; break;
        default: w = d; wt = od; break;
    }
    int n0 = blockIdx.x * 64, k0 = blockIdx.y * 64, t = threadIdx.x;
    for (int it = 0; it < 16; ++it) {
        int e = it * 256 + t; int r = e >> 6, cc = e & 63;
        tl[r][cc] = f2bf(w[(size_t)(k0 + r) * DM + n0 + cc]);
    }
    __syncthreads();
    for (int it = 0; it < 16; ++it) {
        int e = it * 256 + t; int r = e >> 6, cc = e & 63;
        wt[(size_t)(n0 + r) * DM + k0 + cc] = (u16)tl[cc][r];
    }
}

// ---------------- aux: per-k-tile global bitmasks + concat QKV bias ----------
__global__ void build_aux(const int* __restrict__ gti, unsigned long long* __restrict__ kmask,
                          const float* __restrict__ bq, const float* __restrict__ bk,
                          const float* __restrict__ bv, float* __restrict__ bias3) {
    int t = threadIdx.x;
    if (t < 32) {
        unsigned long long m = 0ull;
        #pragma unroll
        for (int i = 0; i < 8; ++i) {
            int g = gti[i];
            if ((g >> 6) == t) m |= 1ull << (g & 63);
        }
        kmask[t] = m;
    }
    for (int i = t; i < 1024; i += 256) {
        bias3[i] = bq[i]; bias3[1024 + i] = bk[i]; bias3[2048 + i] = bv[i];
    }
}

// ---------------- LayerNorm: fp32 in -> bf16 out -----------------------------
__global__ __launch_bounds__(256) void ln_kernel(const float* __restrict__ x,
                                                 const float* __restrict__ g,
                                                 const float* __restrict__ b,
                                                 u16* __restrict__ out) {
    int row = blockIdx.x, t = threadIdx.x;
    const float4 v = ((const float4*)(x + (size_t)row * DM))[t];
    float s  = v.x + v.y + v.z + v.w;
    float sq = v.x * v.x + v.y * v.y + v.z * v.z + v.w * v.w;
    #pragma unroll
    for (int m = 1; m < 64; m <<= 1) { s += __shfl_xor(s, m); sq += __shfl_xor(sq, m); }
    __shared__ float ss[4], ssq[4];
    int wv = t >> 6, lane = t & 63;
    if (lane == 0) { ss[wv] = s; ssq[wv] = sq; }
    __syncthreads();
    s  = ss[0] + ss[1] + ss[2] + ss[3];
    sq = ssq[0] + ssq[1] + ssq[2] + ssq[3];
    float mean = s * (1.f / DM);
    float var  = sq * (1.f / DM) - mean * mean;
    float rs   = rsqrtf(var + 1e-5f);
    float4 gg = ((const float4*)g)[t];
    float4 bb = ((const float4*)b)[t];
    ushort4 o;
    o.x = f2bf((v.x - mean) * rs * gg.x + bb.x);
    o.y = f2bf((v.y - mean) * rs * gg.y + bb.y);
    o.z = f2bf((v.z - mean) * rs * gg.z + bb.z);
    o.w = f2bf((v.w - mean) * rs * gg.w + bb.w);
    ((ushort4*)(out + (size_t)row * DM))[t] = o;
}

// ---------------- RoPE: qkv bf16 [B,S,3072] -> head-major bf16 [B,H,S,Dh] ----
// Q is prescaled by 1/sqrt(Dh)=0.125 so attention needs no score scaling.
__global__ __launch_bounds__(256) void rope_kernel(const u16* __restrict__ qkv,
                                                   u16* __restrict__ qh,
                                                   u16* __restrict__ kh) {
    int idx = blockIdx.x * 256 + threadIdx.x;   // B*H*S*32 threads
    int d = idx & 31;
    int s = (idx >> 5) & (SS - 1);
    int h = (idx >> 16) & (NH - 1);
    int b = idx >> 20;
    size_t src = ((size_t)(b * SS + s)) * 3072 + h * DH + d;
    size_t dst = ((size_t)((b * NH + h) * SS + s)) * DH + d;
    float inv = powf(10000.f, -(float)d * (1.f / 32.f));
    float ang = (float)s * inv;
    float sn, cs;
    sincosf(ang, &sn, &cs);
    const float QSC = 0.125f;
    float x1 = bf2f(qkv[src]), x2 = bf2f(qkv[src + 32]);
    qh[dst]      = f2bf((x1 * cs - x2 * sn) * QSC);
    qh[dst + 32] = f2bf((x2 * cs + x1 * sn) * QSC);
    x1 = bf2f(qkv[src + 1024]); x2 = bf2f(qkv[src + 1024 + 32]);
    kh[dst]      = f2bf(x1 * cs - x2 * sn);
    kh[dst + 32] = f2bf(x2 * cs + x1 * sn);
}

// ---------------- V transpose: qkv [B,S,3072] (v at +2048) -> [B,H,Dh,S] -----
__global__ __launch_bounds__(256) void vtrans_kernel(const u16* __restrict__ qkv,
                                                     u16* __restrict__ vt) {
    __shared__ unsigned tile[64][65];
    int st = blockIdx.x, bh = blockIdx.y;
    int b = bh >> 4, h = bh & 15, t = threadIdx.x;
    const u16* src = qkv + ((size_t)b * SS + st * 64) * 3072 + 2048 + h * DH;
    for (int it = 0; it < 16; ++it) {
        int e = it * 256 + t; int r = e >> 6, c = e & 63;       // r: s, c: d
        tile[r][c] = src[(size_t)r * 3072 + c];
    }
    __syncthreads();
    u16* dst = vt + ((size_t)bh * DH) * SS + st * 64;
    for (int it = 0; it < 16; ++it) {
        int e = it * 256 + t; int d = e >> 6, s = e & 63;
        dst[(size_t)d * SS + s] = (u16)tile[s][d];
    }
}

// ---------------- GEMM: C[M,N] = A[M,K](bf16) * Bt[N,K](bf16)^T + bias -------
// MODE 0: +bias -> bf16 ; MODE 1: +bias+res -> fp32 ; MODE 2: gelu(+bias) -> bf16
// LDS rows are 32 u16 (64B, 4 chunks); xor-swizzle slot = chunk ^ ((row>>1)&3).
// Double-buffered: prefetch K-tile k+1 into buf pb^1 during compute of buf pb.
template <int MODE>
__global__ __launch_bounds__(256) void gemm_bt(const u16* __restrict__ A,
                                               const u16* __restrict__ Bt,
                                               const float* __restrict__ bias,
                                               const float* __restrict__ res,
                                               void* __restrict__ Cout,
                                               int M, int N, int K) {
    const int bm = blockIdx.y * 128, bn = blockIdx.x * 128;
    const int t = threadIdx.x, wv = t >> 6, lane = t & 63;
    const int lr = lane & 15, lq = lane >> 4;
    const int wm = (wv >> 1) * 64, wn = (wv & 1) * 64;
    __shared__ __align__(16) u16 As[2][128 * 32];   // [m][k] swizzled
    __shared__ __align__(16) u16 Bs[2][128 * 32];   // [n][k] swizzled
    f32x4 acc[4][4] = {};

    const int r0 = t >> 2,        sl0 = t & 3;
    const int r1 = (256 + t) >> 2, sl1 = (256 + t) & 3;
    const int gc0 = (sl0 ^ ((r0 >> 1) & 3)) * 8;
    const int gc1 = (sl1 ^ ((r1 >> 1) & 3)) * 8;
    const size_t ldsoff0 = (size_t)(wv * 64) * 8;
    const size_t ldsoff1 = (size_t)(256 + wv * 64) * 8;

    gld_lds16(A + (size_t)(bm + r0) * K + gc0, As[0] + ldsoff0);
    gld_lds16(Bt + (size_t)(bn + r0) * K + gc0, Bs[0] + ldsoff0);
    gld_lds16(A + (size_t)(bm + r1) * K + gc1, As[0] + ldsoff1);
    gld_lds16(Bt + (size_t)(bn + r1) * K + gc1, Bs[0] + ldsoff1);

    int pb = 0;
    for (int k0 = 0; k0 < K; k0 += 32) {
        __syncthreads();                       // buf pb complete for all waves
        if (k0 + 32 < K) {                     // prefetch next tile
            int kn = k0 + 32;
            gld_lds16(A + (size_t)(bm + r0) * K + kn + gc0, As[pb ^ 1] + ldsoff0);
            gld_lds16(Bt + (size_t)(bn + r0) * K + kn + gc0, Bs[pb ^ 1] + ldsoff0);
            gld_lds16(A + (size_t)(bm + r1) * K + kn + gc1, As[pb ^ 1] + ldsoff1);
            gld_lds16(Bt + (size_t)(bn + r1) * K + kn + gc1, Bs[pb ^ 1] + ldsoff1);
        }
        const u16* Ac = As[pb];
        const u16* Bc = Bs[pb];
        bf16x8 af[4], bfr[4];
        #pragma unroll
        for (int mi = 0; mi < 4; ++mi) {
            int row = wm + mi * 16 + lr;
            af[mi] = *(const bf16x8*)&Ac[row * 32 + ((lq ^ ((row >> 1) & 3)) * 8)];
        }
        #pragma unroll
        for (int ni = 0; ni < 4; ++ni) {
            int row = wn + ni * 16 + lr;
            bfr[ni] = *(const bf16x8*)&Bc[row * 32 + ((lq ^ ((row >> 1) & 3)) * 8)];
        }
        #pragma unroll
        for (int mi = 0; mi < 4; ++mi)
            #pragma unroll
            for (int ni = 0; ni < 4; ++ni)
                acc[mi][ni] = __builtin_amdgcn_mfma_f32_16x16x32_bf16(af[mi], bfr[ni], acc[mi][ni], 0, 0, 0);
        pb ^= 1;
    }
    #pragma unroll
    for (int mi = 0; mi < 4; ++mi) {
        int row0 = bm + wm + mi * 16 + lq * 4;
        #pragma unroll
        for (int ni = 0; ni < 4; ++ni) {
            int col = bn + wn + ni * 16 + lr;
            float bv = bias[col];
            #pragma unroll
            for (int r = 0; r < 4; ++r) {
                float v = acc[mi][ni][r] + bv;
                size_t off = (size_t)(row0 + r) * N + col;
                if (MODE == 1) v += res[off];
                if (MODE == 2) v = gelu_f(v);
                if (MODE == 1) ((float*)Cout)[off] = v;
                else           ((u16*)Cout)[off]  = f2bf(v);
            }
        }
    }
}

// ---------------- Flash attention, band 512 + global-K tiles -----------------
// Global-Q rows are NOT handled here (their band-only values are garbage);
// attn_fix_kernel overwrites those 8 rows per (b,h) afterwards. This keeps
// every block's tile count balanced (max ~14) -- no full-causal tail.
__global__ __launch_bounds__(256) void attn_kernel(const u16* __restrict__ qh,
                                                   const u16* __restrict__ kh,
                                                   const u16* __restrict__ vt,
                                                   const unsigned long long* __restrict__ kmask,
                                                   u16* __restrict__ ctx) {
    const int qt = blockIdx.x, bh = blockIdx.y;
    const int b = bh >> 4, h = bh & 15;
    const int t = threadIdx.x, wv = t >> 6, lane = t & 63;
    const int lr = lane & 15, lq = lane >> 4;
    const int q0 = qt * 64;

    __shared__ __align__(16) u16 Qs[64 * 64];
    __shared__ __align__(16) u16 Ks[2][64 * 64];
    __shared__ __align__(16) u16 Vs[2][64 * 64];
    __shared__ __align__(16) u16 Ps[64 * 64];

    const u16* qbase = qh + ((size_t)bh * SS) * DH;
    const u16* kbase = kh + ((size_t)bh * SS) * DH;
    const u16* vbase = vt + ((size_t)bh * DH) * SS;

    // stage Q (swizzled)
    #pragma unroll
    for (int p = 0; p < 2; ++p) {
        int c = p * 256 + t; int r = c >> 3, sl = c & 7;
        gld_lds16(qbase + (size_t)(q0 + r) * DH + ((sl ^ (r & 7)) * 8),
                  Qs + (size_t)(p * 256 + wv * 64) * 8);
    }

    float sum_part[4] = {0.f, 0.f, 0.f, 0.f};
    f32x4 acc_o[4] = {};

    const int lim = qt - 8;        // kt >= lim always included (band)
    int cur = 0;
    while (cur < lim && kmask[cur] == 0ull) ++cur;
    // stage first K/V into buf 0
    {
        int k0 = cur * 64;
        #pragma unroll
        for (int p = 0; p < 2; ++p) {
            int c = p * 256 + t; int r = c >> 3; int gc = ((c & 7) ^ (r & 7)) * 8;
            gld_lds16(kbase + (size_t)(k0 + r) * DH + gc, Ks[0] + (size_t)(p * 256 + wv * 64) * 8);
            gld_lds16(vbase + (size_t)r * SS + k0 + gc,  Vs[0] + (size_t)(p * 256 + wv * 64) * 8);
        }
    }
    int pb = 0;
    while (cur >= 0) {
        int nxt = cur + 1;
        while (nxt < lim && kmask[nxt] == 0ull) ++nxt;
        if (nxt > qt) nxt = -1;
        __syncthreads();                       // buf pb ready for all waves
        if (nxt >= 0) {                        // prefetch into other buffer
            int k0n = nxt * 64;
            #pragma unroll
            for (int p = 0; p < 2; ++p) {
                int c = p * 256 + t; int r = c >> 3; int gc = ((c & 7) ^ (r & 7)) * 8;
                gld_lds16(kbase + (size_t)(k0n + r) * DH + gc, Ks[pb ^ 1] + (size_t)(p * 256 + wv * 64) * 8);
                gld_lds16(vbase + (size_t)r * SS + k0n + gc,  Vs[pb ^ 1] + (size_t)(p * 256 + wv * 64) * 8);
            }
        }
        const u16* Kt = Ks[pb];
        const u16* Vt = Vs[pb];
        const int k0 = cur * 64;

        // S = Q K^T (wave strip: 16 q-rows x 64 k-cols)
        f32x4 s_acc[4] = {};
        #pragma unroll
        for (int ks = 0; ks < 2; ++ks) {
            const int arow = wv * 16 + lr;
            bf16x8 af = *(const bf16x8*)&Qs[arow * 64 + (((ks * 4 + lq) ^ (arow & 7)) * 8)];
            #pragma unroll
            for (int ni = 0; ni < 4; ++ni) {
                const int brow = ni * 16 + lr;
                bf16x8 bfr = *(const bf16x8*)&Kt[brow * 64 + (((ks * 4 + lq) ^ (brow & 7)) * 8)];
                s_acc[ni] = __builtin_amdgcn_mfma_f32_16x16x32_bf16(af, bfr, s_acc[ni], 0, 0, 0);
            }
        }
        // p = exp(s) (Q prescaled by 0.125); masked lanes -> 0  (block-uniform mode)
        float sv[4][4];
        if (cur >= qt - 7 && cur != qt) {                    // FULL: no mask
            #pragma unroll
            for (int ni = 0; ni < 4; ++ni)
                #pragma unroll
                for (int r = 0; r < 4; ++r) sv[ni][r] = __expf(s_acc[ni][r]);
        } else if (cur == qt) {                              // DIAG: causal only
            #pragma unroll
            for (int ni = 0; ni < 4; ++ni) {
                int j = ni * 16 + lr;
                #pragma unroll
                for (int r = 0; r < 4; ++r) {
                    int i = wv * 16 + lq * 4 + r;
                    float p = __expf(s_acc[ni][r]);
                    sv[ni][r] = (j <= i) ? p : 0.f;
                }
            }
        } else {                                             // MASKED: band edge / global-K
            unsigned long long cm = kmask[cur];
            #pragma unroll
            for (int ni = 0; ni < 4; ++ni) {
                int j = k0 + ni * 16 + lr;
                bool gj = (cm >> (ni * 16 + lr)) & 1ull;
                #pragma unroll
                for (int r = 0; r < 4; ++r) {
                    int i = q0 + wv * 16 + lq * 4 + r;
                    bool ok = ((i - j) < 512) | gj;
                    float p = __expf(s_acc[ni][r]);
                    sv[ni][r] = ok ? p : 0.f;
                }
            }
        }
        // accumulate l partials + P -> LDS (wave-private strip, swizzled)
        #pragma unroll
        for (int ni = 0; ni < 4; ++ni) {
            int col = ni * 16 + lr;
            #pragma unroll
            for (int r = 0; r < 4; ++r) {
                int row = wv * 16 + lq * 4 + r;
                sum_part[r] += sv[ni][r];
                Ps[row * 64 + (((col >> 3) ^ (row & 7)) * 8) + (col & 7)] = f2bf(sv[ni][r]);
            }
        }
        // O += P V   (no barrier needed: Ps strip is wave-private)
        #pragma unroll
        for (int ks = 0; ks < 2; ++ks) {
            const int arow = wv * 16 + lr;
            bf16x8 af = *(const bf16x8*)&Ps[arow * 64 + (((ks * 4 + lq) ^ (arow & 7)) * 8)];
            #pragma unroll
            for (int ni = 0; ni < 4; ++ni) {
                const int brow = ni * 16 + lr;
                bf16x8 bfr = *(const bf16x8*)&Vt[brow * 64 + (((ks * 4 + lq) ^ (brow & 7)) * 8)];
                acc_o[ni] = __builtin_amdgcn_mfma_f32_16x16x32_bf16(af, bfr, acc_o[ni], 0, 0, 0);
            }
        }
        cur = nxt; pb ^= 1;
    }
    // epilogue: one cross-lane reduce for l, then ctx = O / l
    float inv_l[4];
    #pragma unroll
    for (int r = 0; r < 4; ++r) {
        float ls = sum_part[r];
        #pragma unroll
        for (int m = 1; m < 16; m <<= 1) ls += __shfl_xor(ls, m, 16);
        inv_l[r] = 1.f / ls;
    }
    u16* obase = ctx + ((size_t)b * SS) * DM + h * DH;
    #pragma unroll
    for (int ni = 0; ni < 4; ++ni)
        #pragma unroll
        for (int r = 0; r < 4; ++r) {
            int i = q0 + wv * 16 + lq * 4 + r;
            obase[(size_t)i * DM + ni * 16 + lr] = f2bf(acc_o[ni][r] * inv_l[r]);
        }
}

// ---------------- Global-row fixup: full causal attention for the 8 global
// q-rows of each (b,h). Grid (8, 32). Wave handles 4 keys/iter, lane = dim.
__global__ __launch_bounds__(256) void attn_fix_kernel(const u16* __restrict__ qh,
                                                       const u16* __restrict__ kh,
                                                       const u16* __restrict__ qkv,
                                                       const int* __restrict__ gti,
                                                       u16* __restrict__ ctx) {
    const int gidx = blockIdx.x, bh = blockIdx.y;
    const int b = bh >> 4, h = bh & 15;
    const int t = threadIdx.x, wv = t >> 6, d = t & 63;
    const int i = gti[gidx];

    const float qd = bf2f(qh[((size_t)bh * SS + i) * DH + d]);   // RoPE'd, prescaled
    const u16* kb = kh + (size_t)bh * SS * DH;
    const u16* vb = qkv + 2048 + h * DH;                          // + (b*SS+j)*3072

    float od = 0.f, l = 0.f;
    for (int j0 = wv * 4; j0 <= i; j0 += 16) {
        float s[4];
        int jc[4];
        #pragma unroll
        for (int u = 0; u < 4; ++u) {
            int j = j0 + u;
            jc[u] = j <= i ? j : i;                               // clamp (guarded below)
            s[u] = qd * bf2f(kb[(size_t)jc[u] * DH + d]);
        }
        #pragma unroll
        for (int u = 0; u < 4; ++u) {
            float x = s[u];
            #pragma unroll
            for (int m = 1; m < 64; m <<= 1) x += __shfl_xor(x, m);
            s[u] = x;
        }
        #pragma unroll
        for (int u = 0; u < 4; ++u) {
            float p = (j0 + u <= i) ? __expf(s[u]) : 0.f;
            float v = bf2f(vb[(size_t)(b * SS + jc[u]) * 3072 + d]);
            od += p * v;
            l += p;
        }
    }
    __shared__ float so[4][64];
    __shared__ float sl[4];
    so[wv][d] = od;
    if (d == 0) sl[wv] = l;
    __syncthreads();
    if (wv == 0) {
        float ot = so[0][d] + so[1][d] + so[2][d] + so[3][d];
        float lt = sl[0] + sl[1] + sl[2] + sl[3];
        ctx[((size_t)b * SS + i) * DM + h * DH + d] = f2bf(ot / lt);
    }
}

extern "C" void kernel_launch(void* const* d_in, const int* in_sizes, int n_in,
                              void* d_out, int out_size, void* d_ws, size_t ws_size,
                              hipStream_t stream) {
    (void)in_sizes; (void)n_in; (void)out_size; (void)ws_size;
    const float* hidden = (const float*)d_in[0];
    const float* ln1_g  = (const float*)d_in[1];
    const float* ln1_b  = (const float*)d_in[2];
    const float* wq = (const float*)d_in[3];  const float* bq = (const float*)d_in[4];
    const float* wk = (const float*)d_in[5];  const float* bk = (const float*)d_in[6];
    const float* wv = (const float*)d_in[7];  const float* bv = (const float*)d_in[8];
    const float* wo = (const float*)d_in[9];  const float* bo = (const float*)d_in[10];
    const float* ln2_g = (const float*)d_in[11];
    const float* ln2_b = (const float*)d_in[12];
    const float* w1 = (const float*)d_in[13]; const float* b1 = (const float*)d_in[14];
    const float* w2 = (const float*)d_in[15]; const float* b2 = (const float*)d_in[16];
    const int*  gti = (const int*)d_in[17];

    char* ws = (char*)d_ws;
    const size_t MB = 1u << 20;
    u16* wqt  = (u16*)(ws + 0 * MB);    // [3072][1024] contiguous (wq|wk|wv transposed)
    u16* wkt  = (u16*)(ws + 2 * MB);
    u16* wvt  = (u16*)(ws + 4 * MB);
    u16* wot  = (u16*)(ws + 6 * MB);
    u16* w1t  = (u16*)(ws + 8 * MB);    // [4096][1024]
    u16* w2t  = (u16*)(ws + 16 * MB);   // [1024][4096]
    u16* xb   = (u16*)(ws + 24 * MB);   // ln1 out; reused as ctx after QKV
    u16* ctx  = xb;
    u16* qkv  = (u16*)(ws + 32 * MB);   // [4096][3072] bf16, 24MB (32..56)
    u16* qhb  = (u16*)(ws + 56 * MB);
    u16* khb  = (u16*)(ws + 64 * MB);
    u16* vtb  = (u16*)(ws + 72 * MB);
    float* hb = (float*)(ws + 80 * MB); // fp32 residual h, 16MB
    u16* act  = (u16*)(ws + 32 * MB);   // 32MB (32..64): qkv+qhb dead after fixup
    u16* yb   = (u16*)(ws + 64 * MB);   // reuses khb (dead after fixup)
    unsigned long long* kmask = (unsigned long long*)(ws + 96 * MB);
    float* bias3 = (float*)(ws + 96 * MB + 4096);

    wtrans4_kernel<<<dim3(16, 16, 4), 256, 0, stream>>>(wq, wk, wv, wo, wqt, wkt, wvt, wot);
    wtrans_kernel<<<dim3(64, 16), 256, 0, stream>>>(w1, w1t, DM, DFF);
    wtrans_kernel<<<dim3(16, 64), 256, 0, stream>>>(w2, w2t, DFF, DM);
    build_aux<<<1, 256, 0, stream>>>(gti, kmask, bq, bk, bv, bias3);

    ln_kernel<<<NB * SS, 256, 0, stream>>>(hidden, ln1_g, ln1_b, xb);

    // fused QKV: A[4096x1024] * [wq|wk|wv]^T -> qkv[4096x3072]
    gemm_bt<0><<<dim3(24, 32), 256, 0, stream>>>(xb, wqt, bias3, nullptr, qkv, NB * SS, 3072, DM);

    rope_kernel<<<(NB * NH * SS * 32) / 256, 256, 0, stream>>>(qkv, qhb, khb);
    vtrans_kernel<<<dim3(SS / 64, NB * NH), 256, 0, stream>>>(qkv, vtb);

    attn_kernel<<<dim3(SS / 64, NB * NH), 256, 0, stream>>>(qhb, khb, vtb, kmask, ctx);
    attn_fix_kernel<<<dim3(8, NB * NH), 256, 0, stream>>>(qhb, khb, qkv, gti, ctx);

    gemm_bt<1><<<dim3(8, 32), 256, 0, stream>>>(ctx, wot, bo, hidden, hb, NB * SS, DM, DM);
    ln_kernel<<<NB * SS, 256, 0, stream>>>(hb, ln2_g, ln2_b, yb);
    gemm_bt<2><<<dim3(32, 32), 256, 0, stream>>>(yb, w1t, b1, nullptr, act, NB * SS, DFF, DM);
    gemm_bt<1><<<dim3(8, 32), 256, 0, stream>>>(act, w2t, b2, hb, d_out, NB * SS, DM, DFF);
}

// Round 7
// 410.005 us; speedup vs baseline: 1.1205x; 1.1205x over previous
//
#include <hip/hip_runtime.h>

typedef unsigned short u16;
typedef __bf16 bf16x8 __attribute__((ext_vector_type(8)));
typedef short s16x8 __attribute__((ext_vector_type(8)));
typedef float f32x4 __attribute__((ext_vector_type(4)));

#define NB 2
#define SS 2048
#define DM 1024
#define NH 16
#define DH 64
#define DFF 4096

__device__ __forceinline__ u16 f2bf(float f) {
    unsigned u = __float_as_uint(f);
    u += 0x7fff + ((u >> 16) & 1);   // RNE
    return (u16)(u >> 16);
}
__device__ __forceinline__ float bf2f(u16 h) {
    return __uint_as_float(((unsigned)h) << 16);
}
// async global->LDS, 16B per lane. LDS dest must be wave-uniform base + lane*16.
__device__ __forceinline__ void gld_lds16(const void* g, void* l) {
    __builtin_amdgcn_global_load_lds(
        (const __attribute__((address_space(1))) unsigned int*)(size_t)g,
        (__attribute__((address_space(3))) unsigned int*)(unsigned)(size_t)l,
        16, 0, 0);
}
__device__ __forceinline__ float gelu_f(float x) {
    return 0.5f * x * (1.f + erff(x * 0.70710678118654752f));
}

// ---------------- weight convert + transpose: w[K][N] fp32 -> wt[N][K] bf16 ----
__global__ void wtrans_kernel(const float* __restrict__ w, u16* __restrict__ wt,
                              int K, int N) {
    __shared__ unsigned tl[64][65];
    int n0 = blockIdx.x * 64, k0 = blockIdx.y * 64, t = threadIdx.x;
    for (int it = 0; it < 16; ++it) {
        int e = it * 256 + t; int r = e >> 6, c = e & 63;       // r: k, c: n
        tl[r][c] = f2bf(w[(size_t)(k0 + r) * N + n0 + c]);
    }
    __syncthreads();
    for (int it = 0; it < 16; ++it) {
        int e = it * 256 + t; int r = e >> 6, c = e & 63;       // r: n, c: k
        wt[(size_t)(n0 + r) * K + k0 + c] = (u16)tl[c][r];
    }
}

// batched version for the four 1024x1024 projection weights
__global__ void wtrans4_kernel(const float* __restrict__ a, const float* __restrict__ b,
                               const float* __restrict__ c, const float* __restrict__ d,
                               u16* __restrict__ oa, u16* __restrict__ ob,
                               u16* __restrict__ oc, u16* __restrict__ od) {
    __shared__ unsigned tl[64][65];
    const float* w; u16* wt;
    switch (blockIdx.z) {
        case 0: w = a; wt = oa; break;
        case 1: w = b; wt = ob; break;
        case 2: w = c; wt = oc; break;
        default: w = d; wt = od; break;
    }
    int n0 = blockIdx.x * 64, k0 = blockIdx.y * 64, t = threadIdx.x;
    for (int it = 0; it < 16; ++it) {
        int e = it * 256 + t; int r = e >> 6, cc = e & 63;
        tl[r][cc] = f2bf(w[(size_t)(k0 + r) * DM + n0 + cc]);
    }
    __syncthreads();
    for (int it = 0; it < 16; ++it) {
        int e = it * 256 + t; int r = e >> 6, cc = e & 63;
        wt[(size_t)(n0 + r) * DM + k0 + cc] = (u16)tl[cc][r];
    }
}

// ---------------- aux: per-k-tile global bitmasks + concat QKV bias ----------
__global__ void build_aux(const int* __restrict__ gti, unsigned long long* __restrict__ kmask,
                          const float* __restrict__ bq, const float* __restrict__ bk,
                          const float* __restrict__ bv, float* __restrict__ bias3) {
    int t = threadIdx.x;
    if (t < 32) {
        unsigned long long m = 0ull;
        #pragma unroll
        for (int i = 0; i < 8; ++i) {
            int g = gti[i];
            if ((g >> 6) == t) m |= 1ull << (g & 63);
        }
        kmask[t] = m;
    }
    for (int i = t; i < 1024; i += 256) {
        bias3[i] = bq[i]; bias3[1024 + i] = bk[i]; bias3[2048 + i] = bv[i];
    }
}

// ---------------- LayerNorm: fp32 in -> bf16 out -----------------------------
__global__ __launch_bounds__(256) void ln_kernel(const float* __restrict__ x,
                                                 const float* __restrict__ g,
                                                 const float* __restrict__ b,
                                                 u16* __restrict__ out) {
    int row = blockIdx.x, t = threadIdx.x;
    const float4 v = ((const float4*)(x + (size_t)row * DM))[t];
    float s  = v.x + v.y + v.z + v.w;
    float sq = v.x * v.x + v.y * v.y + v.z * v.z + v.w * v.w;
    #pragma unroll
    for (int m = 1; m < 64; m <<= 1) { s += __shfl_xor(s, m); sq += __shfl_xor(sq, m); }
    __shared__ float ss[4], ssq[4];
    int wv = t >> 6, lane = t & 63;
    if (lane == 0) { ss[wv] = s; ssq[wv] = sq; }
    __syncthreads();
    s  = ss[0] + ss[1] + ss[2] + ss[3];
    sq = ssq[0] + ssq[1] + ssq[2] + ssq[3];
    float mean = s * (1.f / DM);
    float var  = sq * (1.f / DM) - mean * mean;
    float rs   = rsqrtf(var + 1e-5f);
    float4 gg = ((const float4*)g)[t];
    float4 bb = ((const float4*)b)[t];
    ushort4 o;
    o.x = f2bf((v.x - mean) * rs * gg.x + bb.x);
    o.y = f2bf((v.y - mean) * rs * gg.y + bb.y);
    o.z = f2bf((v.z - mean) * rs * gg.z + bb.z);
    o.w = f2bf((v.w - mean) * rs * gg.w + bb.w);
    ((ushort4*)(out + (size_t)row * DM))[t] = o;
}

// ---------------- RoPE: qkv bf16 [B,S,3072] -> head-major bf16 [B,H,S,Dh] ----
// Q is prescaled by 1/sqrt(Dh)=0.125 so attention needs no score scaling.
__global__ __launch_bounds__(256) void rope_kernel(const u16* __restrict__ qkv,
                                                   u16* __restrict__ qh,
                                                   u16* __restrict__ kh) {
    int idx = blockIdx.x * 256 + threadIdx.x;   // B*H*S*32 threads
    int d = idx & 31;
    int s = (idx >> 5) & (SS - 1);
    int h = (idx >> 16) & (NH - 1);
    int b = idx >> 20;
    size_t src = ((size_t)(b * SS + s)) * 3072 + h * DH + d;
    size_t dst = ((size_t)((b * NH + h) * SS + s)) * DH + d;
    float inv = powf(10000.f, -(float)d * (1.f / 32.f));
    float ang = (float)s * inv;
    float sn, cs;
    sincosf(ang, &sn, &cs);
    const float QSC = 0.125f;
    float x1 = bf2f(qkv[src]), x2 = bf2f(qkv[src + 32]);
    qh[dst]      = f2bf((x1 * cs - x2 * sn) * QSC);
    qh[dst + 32] = f2bf((x2 * cs + x1 * sn) * QSC);
    x1 = bf2f(qkv[src + 1024]); x2 = bf2f(qkv[src + 1024 + 32]);
    kh[dst]      = f2bf(x1 * cs - x2 * sn);
    kh[dst + 32] = f2bf(x2 * cs + x1 * sn);
}

// ---------------- V transpose: qkv [B,S,3072] (v at +2048) -> [B,H,Dh,S] -----
__global__ __launch_bounds__(256) void vtrans_kernel(const u16* __restrict__ qkv,
                                                     u16* __restrict__ vt) {
    __shared__ unsigned tile[64][65];
    int st = blockIdx.x, bh = blockIdx.y;
    int b = bh >> 4, h = bh & 15, t = threadIdx.x;
    const u16* src = qkv + ((size_t)b * SS + st * 64) * 3072 + 2048 + h * DH;
    for (int it = 0; it < 16; ++it) {
        int e = it * 256 + t; int r = e >> 6, c = e & 63;       // r: s, c: d
        tile[r][c] = src[(size_t)r * 3072 + c];
    }
    __syncthreads();
    u16* dst = vt + ((size_t)bh * DH) * SS + st * 64;
    for (int it = 0; it < 16; ++it) {
        int e = it * 256 + t; int d = e >> 6, s = e & 63;
        dst[(size_t)d * SS + s] = (u16)tile[s][d];
    }
}

// ---------------- GEMM: C[M,N] = A[M,K](bf16) * Bt[N,K](bf16)^T + bias -------
// MODE 0: +bias -> bf16 ; MODE 1: +bias+res -> fp32 ; MODE 2: gelu(+bias) -> bf16
// LDS rows are 32 u16 (64B, 4 chunks); xor-swizzle slot = chunk ^ ((row>>1)&3).
// Double-buffered: prefetch K-tile k+1 into buf pb^1 during compute of buf pb.
template <int MODE>
__global__ __launch_bounds__(256) void gemm_bt(const u16* __restrict__ A,
                                               const u16* __restrict__ Bt,
                                               const float* __restrict__ bias,
                                               const float* __restrict__ res,
                                               void* __restrict__ Cout,
                                               int M, int N, int K) {
    const int bm = blockIdx.y * 128, bn = blockIdx.x * 128;
    const int t = threadIdx.x, wv = t >> 6, lane = t & 63;
    const int lr = lane & 15, lq = lane >> 4;
    const int wm = (wv >> 1) * 64, wn = (wv & 1) * 64;
    __shared__ __align__(16) u16 As[2][128 * 32];   // [m][k] swizzled
    __shared__ __align__(16) u16 Bs[2][128 * 32];   // [n][k] swizzled
    f32x4 acc[4][4] = {};

    const int r0 = t >> 2,        sl0 = t & 3;
    const int r1 = (256 + t) >> 2, sl1 = (256 + t) & 3;
    const int gc0 = (sl0 ^ ((r0 >> 1) & 3)) * 8;
    const int gc1 = (sl1 ^ ((r1 >> 1) & 3)) * 8;
    const size_t ldsoff0 = (size_t)(wv * 64) * 8;
    const size_t ldsoff1 = (size_t)(256 + wv * 64) * 8;

    gld_lds16(A + (size_t)(bm + r0) * K + gc0, As[0] + ldsoff0);
    gld_lds16(Bt + (size_t)(bn + r0) * K + gc0, Bs[0] + ldsoff0);
    gld_lds16(A + (size_t)(bm + r1) * K + gc1, As[0] + ldsoff1);
    gld_lds16(Bt + (size_t)(bn + r1) * K + gc1, Bs[0] + ldsoff1);

    int pb = 0;
    for (int k0 = 0; k0 < K; k0 += 32) {
        __syncthreads();                       // buf pb complete for all waves
        if (k0 + 32 < K) {                     // prefetch next tile
            int kn = k0 + 32;
            gld_lds16(A + (size_t)(bm + r0) * K + kn + gc0, As[pb ^ 1] + ldsoff0);
            gld_lds16(Bt + (size_t)(bn + r0) * K + kn + gc0, Bs[pb ^ 1] + ldsoff0);
            gld_lds16(A + (size_t)(bm + r1) * K + kn + gc1, As[pb ^ 1] + ldsoff1);
            gld_lds16(Bt + (size_t)(bn + r1) * K + kn + gc1, Bs[pb ^ 1] + ldsoff1);
        }
        const u16* Ac = As[pb];
        const u16* Bc = Bs[pb];
        bf16x8 af[4], bfr[4];
        #pragma unroll
        for (int mi = 0; mi < 4; ++mi) {
            int row = wm + mi * 16 + lr;
            af[mi] = *(const bf16x8*)&Ac[row * 32 + ((lq ^ ((row >> 1) & 3)) * 8)];
        }
        #pragma unroll
        for (int ni = 0; ni < 4; ++ni) {
            int row = wn + ni * 16 + lr;
            bfr[ni] = *(const bf16x8*)&Bc[row * 32 + ((lq ^ ((row >> 1) & 3)) * 8)];
        }
        #pragma unroll
        for (int mi = 0; mi < 4; ++mi)
            #pragma unroll
            for (int ni = 0; ni < 4; ++ni)
                acc[mi][ni] = __builtin_amdgcn_mfma_f32_16x16x32_bf16(af[mi], bfr[ni], acc[mi][ni], 0, 0, 0);
        pb ^= 1;
    }
    #pragma unroll
    for (int mi = 0; mi < 4; ++mi) {
        int row0 = bm + wm + mi * 16 + lq * 4;
        #pragma unroll
        for (int ni = 0; ni < 4; ++ni) {
            int col = bn + wn + ni * 16 + lr;
            float bv = bias[col];
            #pragma unroll
            for (int r = 0; r < 4; ++r) {
                float v = acc[mi][ni][r] + bv;
                size_t off = (size_t)(row0 + r) * N + col;
                if (MODE == 1) v += res[off];
                if (MODE == 2) v = gelu_f(v);
                if (MODE == 1) ((float*)Cout)[off] = v;
                else           ((u16*)Cout)[off]  = f2bf(v);
            }
        }
    }
}

// ---------------- Flash attention, band 512 + global-K tiles -----------------
// Global-Q rows are NOT handled here (their band-only values are garbage);
// attn_fix_kernel overwrites those 8 rows per (b,h) afterwards. This keeps
// every block's tile count balanced (max ~14) -- no full-causal tail.
__global__ __launch_bounds__(256) void attn_kernel(const u16* __restrict__ qh,
                                                   const u16* __restrict__ kh,
                                                   const u16* __restrict__ vt,
                                                   const unsigned long long* __restrict__ kmask,
                                                   u16* __restrict__ ctx) {
    const int qt = blockIdx.x, bh = blockIdx.y;
    const int b = bh >> 4, h = bh & 15;
    const int t = threadIdx.x, wv = t >> 6, lane = t & 63;
    const int lr = lane & 15, lq = lane >> 4;
    const int q0 = qt * 64;

    __shared__ __align__(16) u16 Qs[64 * 64];
    __shared__ __align__(16) u16 Ks[2][64 * 64];
    __shared__ __align__(16) u16 Vs[2][64 * 64];
    __shared__ __align__(16) u16 Ps[64 * 64];

    const u16* qbase = qh + ((size_t)bh * SS) * DH;
    const u16* kbase = kh + ((size_t)bh * SS) * DH;
    const u16* vbase = vt + ((size_t)bh * DH) * SS;

    // stage Q (swizzled)
    #pragma unroll
    for (int p = 0; p < 2; ++p) {
        int c = p * 256 + t; int r = c >> 3, sl = c & 7;
        gld_lds16(qbase + (size_t)(q0 + r) * DH + ((sl ^ (r & 7)) * 8),
                  Qs + (size_t)(p * 256 + wv * 64) * 8);
    }

    float sum_part[4] = {0.f, 0.f, 0.f, 0.f};
    f32x4 acc_o[4] = {};

    const int lim = qt - 8;        // kt >= lim always included (band)
    int cur = 0;
    while (cur < lim && kmask[cur] == 0ull) ++cur;
    // stage first K/V into buf 0
    {
        int k0 = cur * 64;
        #pragma unroll
        for (int p = 0; p < 2; ++p) {
            int c = p * 256 + t; int r = c >> 3; int gc = ((c & 7) ^ (r & 7)) * 8;
            gld_lds16(kbase + (size_t)(k0 + r) * DH + gc, Ks[0] + (size_t)(p * 256 + wv * 64) * 8);
            gld_lds16(vbase + (size_t)r * SS + k0 + gc,  Vs[0] + (size_t)(p * 256 + wv * 64) * 8);
        }
    }
    int pb = 0;
    while (cur >= 0) {
        int nxt = cur + 1;
        while (nxt < lim && kmask[nxt] == 0ull) ++nxt;
        if (nxt > qt) nxt = -1;
        __syncthreads();                       // buf pb ready for all waves
        if (nxt >= 0) {                        // prefetch into other buffer
            int k0n = nxt * 64;
            #pragma unroll
            for (int p = 0; p < 2; ++p) {
                int c = p * 256 + t; int r = c >> 3; int gc = ((c & 7) ^ (r & 7)) * 8;
                gld_lds16(kbase + (size_t)(k0n + r) * DH + gc, Ks[pb ^ 1] + (size_t)(p * 256 + wv * 64) * 8);
                gld_lds16(vbase + (size_t)r * SS + k0n + gc,  Vs[pb ^ 1] + (size_t)(p * 256 + wv * 64) * 8);
            }
        }
        const u16* Kt = Ks[pb];
        const u16* Vt = Vs[pb];
        const int k0 = cur * 64;

        // S = Q K^T (wave strip: 16 q-rows x 64 k-cols)
        f32x4 s_acc[4] = {};
        #pragma unroll
        for (int ks = 0; ks < 2; ++ks) {
            const int arow = wv * 16 + lr;
            bf16x8 af = *(const bf16x8*)&Qs[arow * 64 + (((ks * 4 + lq) ^ (arow & 7)) * 8)];
            #pragma unroll
            for (int ni = 0; ni < 4; ++ni) {
                const int brow = ni * 16 + lr;
                bf16x8 bfr = *(const bf16x8*)&Kt[brow * 64 + (((ks * 4 + lq) ^ (brow & 7)) * 8)];
                s_acc[ni] = __builtin_amdgcn_mfma_f32_16x16x32_bf16(af, bfr, s_acc[ni], 0, 0, 0);
            }
        }
        // p = exp(s) (Q prescaled by 0.125); masked lanes -> 0  (block-uniform mode)
        float sv[4][4];
        if (cur >= qt - 7 && cur != qt) {                    // FULL: no mask
            #pragma unroll
            for (int ni = 0; ni < 4; ++ni)
                #pragma unroll
                for (int r = 0; r < 4; ++r) sv[ni][r] = __expf(s_acc[ni][r]);
        } else if (cur == qt) {                              // DIAG: causal only
            #pragma unroll
            for (int ni = 0; ni < 4; ++ni) {
                int j = ni * 16 + lr;
                #pragma unroll
                for (int r = 0; r < 4; ++r) {
                    int i = wv * 16 + lq * 4 + r;
                    float p = __expf(s_acc[ni][r]);
                    sv[ni][r] = (j <= i) ? p : 0.f;
                }
            }
        } else {                                             // MASKED: band edge / global-K
            unsigned long long cm = kmask[cur];
            #pragma unroll
            for (int ni = 0; ni < 4; ++ni) {
                int j = k0 + ni * 16 + lr;
                bool gj = (cm >> (ni * 16 + lr)) & 1ull;
                #pragma unroll
                for (int r = 0; r < 4; ++r) {
                    int i = q0 + wv * 16 + lq * 4 + r;
                    bool ok = ((i - j) < 512) | gj;
                    float p = __expf(s_acc[ni][r]);
                    sv[ni][r] = ok ? p : 0.f;
                }
            }
        }
        // accumulate l partials + P -> LDS (wave-private strip, swizzled)
        #pragma unroll
        for (int ni = 0; ni < 4; ++ni) {
            int col = ni * 16 + lr;
            #pragma unroll
            for (int r = 0; r < 4; ++r) {
                int row = wv * 16 + lq * 4 + r;
                sum_part[r] += sv[ni][r];
                Ps[row * 64 + (((col >> 3) ^ (row & 7)) * 8) + (col & 7)] = f2bf(sv[ni][r]);
            }
        }
        // O += P V   (no barrier needed: Ps strip is wave-private)
        #pragma unroll
        for (int ks = 0; ks < 2; ++ks) {
            const int arow = wv * 16 + lr;
            bf16x8 af = *(const bf16x8*)&Ps[arow * 64 + (((ks * 4 + lq) ^ (arow & 7)) * 8)];
            #pragma unroll
            for (int ni = 0; ni < 4; ++ni) {
                const int brow = ni * 16 + lr;
                bf16x8 bfr = *(const bf16x8*)&Vt[brow * 64 + (((ks * 4 + lq) ^ (brow & 7)) * 8)];
                acc_o[ni] = __builtin_amdgcn_mfma_f32_16x16x32_bf16(af, bfr, acc_o[ni], 0, 0, 0);
            }
        }
        cur = nxt; pb ^= 1;
    }
    // epilogue: one cross-lane reduce for l, then ctx = O / l
    float inv_l[4];
    #pragma unroll
    for (int r = 0; r < 4; ++r) {
        float ls = sum_part[r];
        #pragma unroll
        for (int m = 1; m < 16; m <<= 1) ls += __shfl_xor(ls, m, 16);
        inv_l[r] = 1.f / ls;
    }
    u16* obase = ctx + ((size_t)b * SS) * DM + h * DH;
    #pragma unroll
    for (int ni = 0; ni < 4; ++ni)
        #pragma unroll
        for (int r = 0; r < 4; ++r) {
            int i = q0 + wv * 16 + lq * 4 + r;
            obase[(size_t)i * DM + ni * 16 + lr] = f2bf(acc_o[ni][r] * inv_l[r]);
        }
}

// ---------------- Global-row fixup v2: full causal attention for the 8 global
// q-rows of each (b,h). Grid (8, 32). lane = key: each lane owns one key j,
// computes the dot in-register (q broadcast from LDS), p=exp, accumulates
// p*v_j into a per-lane 64-float O accumulator. ZERO cross-lane ops in the
// loop; one butterfly reduce at the end. All register arrays statically
// indexed (scratch-demotion hazard).
__global__ __launch_bounds__(256) void attn_fix_kernel(const u16* __restrict__ qh,
                                                       const u16* __restrict__ kh,
                                                       const u16* __restrict__ qkv,
                                                       const int* __restrict__ gti,
                                                       u16* __restrict__ ctx) {
    const int gidx = blockIdx.x, bh = blockIdx.y;
    const int b = bh >> 4, h = bh & 15;
    const int t = threadIdx.x, wv = t >> 6, lane = t & 63;
    const int i = gti[gidx];

    __shared__ float qsh[64];
    if (t < 64) qsh[t] = bf2f(qh[((size_t)bh * SS + i) * DH + t]);   // RoPE'd, prescaled
    __syncthreads();
    float qreg[64];
    #pragma unroll
    for (int c = 0; c < 16; ++c) {
        float4 qv = ((const float4*)qsh)[c];   // same addr all lanes: broadcast
        qreg[c * 4 + 0] = qv.x; qreg[c * 4 + 1] = qv.y;
        qreg[c * 4 + 2] = qv.z; qreg[c * 4 + 3] = qv.w;
    }

    const u16* kb = kh + (size_t)bh * SS * DH;
    const u16* vb = qkv + (size_t)b * SS * 3072 + 2048 + h * DH;   // + j*3072

    float Oacc[64];
    #pragma unroll
    for (int d = 0; d < 64; ++d) Oacc[d] = 0.f;
    float lacc = 0.f;

    for (int j0 = wv * 64; j0 <= i; j0 += 256) {
        const int j = j0 + lane;
        const bool valid = (j <= i);
        const int jc = valid ? j : i;
        // s = q . k_j  (8 independent chunk partials to break the FMA chain)
        const s16x8* krow = (const s16x8*)(kb + (size_t)jc * DH);
        float part[8];
        #pragma unroll
        for (int c = 0; c < 8; ++c) {
            s16x8 kv = krow[c];
            float p0 = 0.f;
            #pragma unroll
            for (int e = 0; e < 8; ++e) p0 += qreg[c * 8 + e] * bf2f((u16)kv[e]);
            part[c] = p0;
        }
        float s = ((part[0] + part[1]) + (part[2] + part[3])) +
                  ((part[4] + part[5]) + (part[6] + part[7]));
        const float p = valid ? __expf(s) : 0.f;
        lacc += p;
        const s16x8* vrow = (const s16x8*)(vb + (size_t)jc * 3072);
        #pragma unroll
        for (int c = 0; c < 8; ++c) {
            s16x8 vv = vrow[c];
            #pragma unroll
            for (int e = 0; e < 8; ++e) Oacc[c * 8 + e] += p * bf2f((u16)vv[e]);
        }
    }
    // butterfly reduce across the wave's 64 key-lanes (once)
    #pragma unroll
    for (int m = 1; m < 64; m <<= 1) {
        lacc += __shfl_xor(lacc, m);
        #pragma unroll
        for (int d = 0; d < 64; ++d) Oacc[d] += __shfl_xor(Oacc[d], m);
    }
    // lane picks element `lane` via static select chain (no dynamic reg index)
    float out = 0.f;
    #pragma unroll
    for (int d = 0; d < 64; ++d) out = (lane == d) ? Oacc[d] : out;
    __shared__ float osum[4][64];
    __shared__ float lsum[4];
    osum[wv][lane] = out;
    if (lane == 0) lsum[wv] = lacc;
    __syncthreads();
    if (wv == 0) {
        float ot = osum[0][lane] + osum[1][lane] + osum[2][lane] + osum[3][lane];
        float lt = lsum[0] + lsum[1] + lsum[2] + lsum[3];
        ctx[((size_t)b * SS + i) * DM + h * DH + lane] = f2bf(ot / lt);
    }
}

extern "C" void kernel_launch(void* const* d_in, const int* in_sizes, int n_in,
                              void* d_out, int out_size, void* d_ws, size_t ws_size,
                              hipStream_t stream) {
    (void)in_sizes; (void)n_in; (void)out_size; (void)ws_size;
    const float* hidden = (const float*)d_in[0];
    const float* ln1_g  = (const float*)d_in[1];
    const float* ln1_b  = (const float*)d_in[2];
    const float* wq = (const float*)d_in[3];  const float* bq = (const float*)d_in[4];
    const float* wk = (const float*)d_in[5];  const float* bk = (const float*)d_in[6];
    const float* wv = (const float*)d_in[7];  const float* bv = (const float*)d_in[8];
    const float* wo = (const float*)d_in[9];  const float* bo = (const float*)d_in[10];
    const float* ln2_g = (const float*)d_in[11];
    const float* ln2_b = (const float*)d_in[12];
    const float* w1 = (const float*)d_in[13]; const float* b1 = (const float*)d_in[14];
    const float* w2 = (const float*)d_in[15]; const float* b2 = (const float*)d_in[16];
    const int*  gti = (const int*)d_in[17];

    char* ws = (char*)d_ws;
    const size_t MB = 1u << 20;
    u16* wqt  = (u16*)(ws + 0 * MB);    // [3072][1024] contiguous (wq|wk|wv transposed)
    u16* wkt  = (u16*)(ws + 2 * MB);
    u16* wvt  = (u16*)(ws + 4 * MB);
    u16* wot  = (u16*)(ws + 6 * MB);
    u16* w1t  = (u16*)(ws + 8 * MB);    // [4096][1024]
    u16* w2t  = (u16*)(ws + 16 * MB);   // [1024][4096]
    u16* xb   = (u16*)(ws + 24 * MB);   // ln1 out; reused as ctx after QKV
    u16* ctx  = xb;
    u16* qkv  = (u16*)(ws + 32 * MB);   // [4096][3072] bf16, 24MB (32..56)
    u16* qhb  = (u16*)(ws + 56 * MB);
    u16* khb  = (u16*)(ws + 64 * MB);
    u16* vtb  = (u16*)(ws + 72 * MB);
    float* hb = (float*)(ws + 80 * MB); // fp32 residual h, 16MB
    u16* act  = (u16*)(ws + 32 * MB);   // 32MB (32..64): qkv+qhb dead after fixup
    u16* yb   = (u16*)(ws + 64 * MB);   // reuses khb (dead after fixup)
    unsigned long long* kmask = (unsigned long long*)(ws + 96 * MB);
    float* bias3 = (float*)(ws + 96 * MB + 4096);

    wtrans4_kernel<<<dim3(16, 16, 4), 256, 0, stream>>>(wq, wk, wv, wo, wqt, wkt, wvt, wot);
    wtrans_kernel<<<dim3(64, 16), 256, 0, stream>>>(w1, w1t, DM, DFF);
    wtrans_kernel<<<dim3(16, 64), 256, 0, stream>>>(w2, w2t, DFF, DM);
    build_aux<<<1, 256, 0, stream>>>(gti, kmask, bq, bk, bv, bias3);

    ln_kernel<<<NB * SS, 256, 0, stream>>>(hidden, ln1_g, ln1_b, xb);

    // fused QKV: A[4096x1024] * [wq|wk|wv]^T -> qkv[4096x3072]
    gemm_bt<0><<<dim3(24, 32), 256, 0, stream>>>(xb, wqt, bias3, nullptr, qkv, NB * SS, 3072, DM);

    rope_kernel<<<(NB * NH * SS * 32) / 256, 256, 0, stream>>>(qkv, qhb, khb);
    vtrans_kernel<<<dim3(SS / 64, NB * NH), 256, 0, stream>>>(qkv, vtb);

    attn_kernel<<<dim3(SS / 64, NB * NH), 256, 0, stream>>>(qhb, khb, vtb, kmask, ctx);
    attn_fix_kernel<<<dim3(8, NB * NH), 256, 0, stream>>>(qhb, khb, qkv, gti, ctx);

    gemm_bt<1><<<dim3(8, 32), 256, 0, stream>>>(ctx, wot, bo, hidden, hb, NB * SS, DM, DM);
    ln_kernel<<<NB * SS, 256, 0, stream>>>(hb, ln2_g, ln2_b, yb);
    gemm_bt<2><<<dim3(32, 32), 256, 0, stream>>>(yb, w1t, b1, nullptr, act, NB * SS, DFF, DM);
    gemm_bt<1><<<dim3(8, 32), 256, 0, stream>>>(act, w2t, b2, hb, d_out, NB * SS, DM, DFF);
}

// Round 8
// 401.495 us; speedup vs baseline: 1.1443x; 1.0212x over previous
//
#include <hip/hip_runtime.h>

typedef unsigned short u16;
typedef __bf16 bf16x8 __attribute__((ext_vector_type(8)));
typedef short s16x8 __attribute__((ext_vector_type(8)));
typedef float f32x4 __attribute__((ext_vector_type(4)));

#define NB 2
#define SS 2048
#define DM 1024
#define NH 16
#define DH 64
#define DFF 4096

__device__ __forceinline__ u16 f2bf(float f) {
    unsigned u = __float_as_uint(f);
    u += 0x7fff + ((u >> 16) & 1);   // RNE
    return (u16)(u >> 16);
}
__device__ __forceinline__ float bf2f(u16 h) {
    return __uint_as_float(((unsigned)h) << 16);
}
// async global->LDS, 16B per lane. LDS dest must be wave-uniform base + lane*16.
__device__ __forceinline__ void gld_lds16(const void* g, void* l) {
    __builtin_amdgcn_global_load_lds(
        (const __attribute__((address_space(1))) unsigned int*)(size_t)g,
        (__attribute__((address_space(3))) unsigned int*)(unsigned)(size_t)l,
        16, 0, 0);
}
__device__ __forceinline__ float gelu_f(float x) {
    return 0.5f * x * (1.f + erff(x * 0.70710678118654752f));
}

// ---------------- weight convert + transpose: w[K][N] fp32 -> wt[N][K] bf16 ----
__global__ void wtrans_kernel(const float* __restrict__ w, u16* __restrict__ wt,
                              int K, int N) {
    __shared__ unsigned tl[64][65];
    int n0 = blockIdx.x * 64, k0 = blockIdx.y * 64, t = threadIdx.x;
    for (int it = 0; it < 16; ++it) {
        int e = it * 256 + t; int r = e >> 6, c = e & 63;       // r: k, c: n
        tl[r][c] = f2bf(w[(size_t)(k0 + r) * N + n0 + c]);
    }
    __syncthreads();
    for (int it = 0; it < 16; ++it) {
        int e = it * 256 + t; int r = e >> 6, c = e & 63;       // r: n, c: k
        wt[(size_t)(n0 + r) * K + k0 + c] = (u16)tl[c][r];
    }
}

// batched version for the four 1024x1024 projection weights
__global__ void wtrans4_kernel(const float* __restrict__ a, const float* __restrict__ b,
                               const float* __restrict__ c, const float* __restrict__ d,
                               u16* __restrict__ oa, u16* __restrict__ ob,
                               u16* __restrict__ oc, u16* __restrict__ od) {
    __shared__ unsigned tl[64][65];
    const float* w; u16* wt;
    switch (blockIdx.z) {
        case 0: w = a; wt = oa; break;
        case 1: w = b; wt = ob; break;
        case 2: w = c; wt = oc; break;
        default: w = d; wt = od; break;
    }
    int n0 = blockIdx.x * 64, k0 = blockIdx.y * 64, t = threadIdx.x;
    for (int it = 0; it < 16; ++it) {
        int e = it * 256 + t; int r = e >> 6, cc = e & 63;
        tl[r][cc] = f2bf(w[(size_t)(k0 + r) * DM + n0 + cc]);
    }
    __syncthreads();
    for (int it = 0; it < 16; ++it) {
        int e = it * 256 + t; int r = e >> 6, cc = e & 63;
        wt[(size_t)(n0 + r) * DM + k0 + cc] = (u16)tl[cc][r];
    }
}

// ---------------- aux: per-k-tile global bitmasks + concat QKV bias ----------
__global__ void build_aux(const int* __restrict__ gti, unsigned long long* __restrict__ kmask,
                          const float* __restrict__ bq, const float* __restrict__ bk,
                          const float* __restrict__ bv, float* __restrict__ bias3) {
    int t = threadIdx.x;
    if (t < 32) {
        unsigned long long m = 0ull;
        #pragma unroll
        for (int i = 0; i < 8; ++i) {
            int g = gti[i];
            if ((g >> 6) == t) m |= 1ull << (g & 63);
        }
        kmask[t] = m;
    }
    for (int i = t; i < 1024; i += 256) {
        bias3[i] = bq[i]; bias3[1024 + i] = bk[i]; bias3[2048 + i] = bv[i];
    }
}

// ---------------- LayerNorm: fp32 in -> bf16 out; INIT also writes iout=x+ib --
template <bool INIT>
__global__ __launch_bounds__(256) void ln_kernel(const float* __restrict__ x,
                                                 const float* __restrict__ g,
                                                 const float* __restrict__ b,
                                                 u16* __restrict__ out,
                                                 const float* __restrict__ ib,
                                                 float* __restrict__ iout) {
    int row = blockIdx.x, t = threadIdx.x;
    const float4 v = ((const float4*)(x + (size_t)row * DM))[t];
    float s  = v.x + v.y + v.z + v.w;
    float sq = v.x * v.x + v.y * v.y + v.z * v.z + v.w * v.w;
    #pragma unroll
    for (int m = 1; m < 64; m <<= 1) { s += __shfl_xor(s, m); sq += __shfl_xor(sq, m); }
    __shared__ float ss[4], ssq[4];
    int wv = t >> 6, lane = t & 63;
    if (lane == 0) { ss[wv] = s; ssq[wv] = sq; }
    __syncthreads();
    s  = ss[0] + ss[1] + ss[2] + ss[3];
    sq = ssq[0] + ssq[1] + ssq[2] + ssq[3];
    float mean = s * (1.f / DM);
    float var  = sq * (1.f / DM) - mean * mean;
    float rs   = rsqrtf(var + 1e-5f);
    float4 gg = ((const float4*)g)[t];
    float4 bb = ((const float4*)b)[t];
    ushort4 o;
    o.x = f2bf((v.x - mean) * rs * gg.x + bb.x);
    o.y = f2bf((v.y - mean) * rs * gg.y + bb.y);
    o.z = f2bf((v.z - mean) * rs * gg.z + bb.z);
    o.w = f2bf((v.w - mean) * rs * gg.w + bb.w);
    ((ushort4*)(out + (size_t)row * DM))[t] = o;
    if (INIT) {
        float4 b2 = ((const float4*)ib)[t];
        float4 iv; iv.x = v.x + b2.x; iv.y = v.y + b2.y; iv.z = v.z + b2.z; iv.w = v.w + b2.w;
        ((float4*)(iout + (size_t)row * DM))[t] = iv;
    }
}

// ---------------- RoPE: qkv bf16 [B,S,3072] -> head-major bf16 [B,H,S,Dh] ----
// Q is prescaled by 1/sqrt(Dh)=0.125 so attention needs no score scaling.
__global__ __launch_bounds__(256) void rope_kernel(const u16* __restrict__ qkv,
                                                   u16* __restrict__ qh,
                                                   u16* __restrict__ kh) {
    int idx = blockIdx.x * 256 + threadIdx.x;   // B*H*S*32 threads
    int d = idx & 31;
    int s = (idx >> 5) & (SS - 1);
    int h = (idx >> 16) & (NH - 1);
    int b = idx >> 20;
    size_t src = ((size_t)(b * SS + s)) * 3072 + h * DH + d;
    size_t dst = ((size_t)((b * NH + h) * SS + s)) * DH + d;
    float inv = powf(10000.f, -(float)d * (1.f / 32.f));
    float ang = (float)s * inv;
    float sn, cs;
    sincosf(ang, &sn, &cs);
    const float QSC = 0.125f;
    float x1 = bf2f(qkv[src]), x2 = bf2f(qkv[src + 32]);
    qh[dst]      = f2bf((x1 * cs - x2 * sn) * QSC);
    qh[dst + 32] = f2bf((x2 * cs + x1 * sn) * QSC);
    x1 = bf2f(qkv[src + 1024]); x2 = bf2f(qkv[src + 1024 + 32]);
    kh[dst]      = f2bf(x1 * cs - x2 * sn);
    kh[dst + 32] = f2bf(x2 * cs + x1 * sn);
}

// ---------------- V transpose: qkv [B,S,3072] (v at +2048) -> [B,H,Dh,S] -----
__global__ __launch_bounds__(256) void vtrans_kernel(const u16* __restrict__ qkv,
                                                     u16* __restrict__ vt) {
    __shared__ unsigned tile[64][65];
    int st = blockIdx.x, bh = blockIdx.y;
    int b = bh >> 4, h = bh & 15, t = threadIdx.x;
    const u16* src = qkv + ((size_t)b * SS + st * 64) * 3072 + 2048 + h * DH;
    for (int it = 0; it < 16; ++it) {
        int e = it * 256 + t; int r = e >> 6, c = e & 63;       // r: s, c: d
        tile[r][c] = src[(size_t)r * 3072 + c];
    }
    __syncthreads();
    u16* dst = vt + ((size_t)bh * DH) * SS + st * 64;
    for (int it = 0; it < 16; ++it) {
        int e = it * 256 + t; int d = e >> 6, s = e & 63;
        dst[(size_t)d * SS + s] = (u16)tile[s][d];
    }
}

// ---------------- GEMM: C[M,N] = A[M,K](bf16) * Bt[N,K](bf16)^T --------------
// MODE 0: +bias -> bf16 ; MODE 1: +bias+res -> fp32 ; MODE 2: gelu(+bias) -> bf16
// MODE 3: split-K partial, atomicAdd fp32 into pre-initialized Cout.
// BK=64 double-buffered: 64 KB LDS (2 blocks/CU), ONE barrier per 32 MFMA.
// LDS rows 64 u16 (128B, 8 chunks); swizzle slot = chunk ^ (row&7) (0 conflicts).
// K = loop extent per z-chunk; ldk = global row stride; koff = blockIdx.z*K.
template <int MODE>
__global__ __launch_bounds__(256) void gemm_bt(const u16* __restrict__ A,
                                               const u16* __restrict__ Bt,
                                               const float* __restrict__ bias,
                                               const float* __restrict__ res,
                                               void* __restrict__ Cout,
                                               int M, int N, int K, int ldk) {
    const int bm = blockIdx.y * 128, bn = blockIdx.x * 128;
    const int koff = blockIdx.z * K;
    const int t = threadIdx.x, wv = t >> 6, lane = t & 63;
    const int lr = lane & 15, lq = lane >> 4;
    const int wm = (wv >> 1) * 64, wn = (wv & 1) * 64;
    __shared__ __align__(16) u16 As[2][128 * 64];   // [m][k] swizzled, 16 KB each
    __shared__ __align__(16) u16 Bs[2][128 * 64];   // [n][k] swizzled
    f32x4 acc[4][4] = {};

    // stage one BK=64 tile (16 KB per matrix): 4 instrs/thread/matrix
    auto stage = [&](int kb, int buf) {
        #pragma unroll
        for (int p = 0; p < 4; ++p) {
            int c = p * 256 + t;                 // chunk id 0..1023, 16B each
            int r = c >> 3;                      // row 0..127
            int gc = ((c & 7) ^ (r & 7)) * 8;    // swizzled source column
            gld_lds16(A + (size_t)(bm + r) * ldk + kb + gc,
                      As[buf] + (size_t)(p * 256 + wv * 64) * 8);
            gld_lds16(Bt + (size_t)(bn + r) * ldk + kb + gc,
                      Bs[buf] + (size_t)(p * 256 + wv * 64) * 8);
        }
    };

    stage(koff, 0);
    int pb = 0;
    for (int k0 = 0; k0 < K; k0 += 64) {
        __syncthreads();                       // buf pb complete for all waves
        if (k0 + 64 < K) stage(koff + k0 + 64, pb ^ 1);
        const u16* Ac = As[pb];
        const u16* Bc = Bs[pb];
        #pragma unroll
        for (int ks = 0; ks < 2; ++ks) {
            bf16x8 af[4], bfr[4];
            #pragma unroll
            for (int mi = 0; mi < 4; ++mi) {
                int row = wm + mi * 16 + lr;
                af[mi] = *(const bf16x8*)&Ac[row * 64 + (((ks * 4 + lq) ^ (row & 7)) * 8)];
            }
            #pragma unroll
            for (int ni = 0; ni < 4; ++ni) {
                int row = wn + ni * 16 + lr;
                bfr[ni] = *(const bf16x8*)&Bc[row * 64 + (((ks * 4 + lq) ^ (row & 7)) * 8)];
            }
            #pragma unroll
            for (int mi = 0; mi < 4; ++mi)
                #pragma unroll
                for (int ni = 0; ni < 4; ++ni)
                    acc[mi][ni] = __builtin_amdgcn_mfma_f32_16x16x32_bf16(af[mi], bfr[ni], acc[mi][ni], 0, 0, 0);
        }
        pb ^= 1;
    }
    #pragma unroll
    for (int mi = 0; mi < 4; ++mi) {
        int row0 = bm + wm + mi * 16 + lq * 4;
        #pragma unroll
        for (int ni = 0; ni < 4; ++ni) {
            int col = bn + wn + ni * 16 + lr;
            float bv = (MODE == 3) ? 0.f : bias[col];
            #pragma unroll
            for (int r = 0; r < 4; ++r) {
                float v = acc[mi][ni][r] + bv;
                size_t off = (size_t)(row0 + r) * N + col;
                if (MODE == 1) v += res[off];
                if (MODE == 2) v = gelu_f(v);
                if (MODE == 0 || MODE == 2) ((u16*)Cout)[off] = f2bf(v);
                else if (MODE == 1)         ((float*)Cout)[off] = v;
                else                        atomicAdd((float*)Cout + off, v);
            }
        }
    }
}

// ---------------- Flash attention, band 512 + global-K tiles -----------------
// Global-Q rows are NOT handled here; attn_fix_kernel overwrites those 8 rows
// per (b,h) afterwards. Keeps every block's tile count balanced (max ~14).
__global__ __launch_bounds__(256) void attn_kernel(const u16* __restrict__ qh,
                                                   const u16* __restrict__ kh,
                                                   const u16* __restrict__ vt,
                                                   const unsigned long long* __restrict__ kmask,
                                                   u16* __restrict__ ctx) {
    const int qt = blockIdx.x, bh = blockIdx.y;
    const int b = bh >> 4, h = bh & 15;
    const int t = threadIdx.x, wv = t >> 6, lane = t & 63;
    const int lr = lane & 15, lq = lane >> 4;
    const int q0 = qt * 64;

    __shared__ __align__(16) u16 Qs[64 * 64];
    __shared__ __align__(16) u16 Ks[2][64 * 64];
    __shared__ __align__(16) u16 Vs[2][64 * 64];
    __shared__ __align__(16) u16 Ps[64 * 64];

    const u16* qbase = qh + ((size_t)bh * SS) * DH;
    const u16* kbase = kh + ((size_t)bh * SS) * DH;
    const u16* vbase = vt + ((size_t)bh * DH) * SS;

    #pragma unroll
    for (int p = 0; p < 2; ++p) {
        int c = p * 256 + t; int r = c >> 3, sl = c & 7;
        gld_lds16(qbase + (size_t)(q0 + r) * DH + ((sl ^ (r & 7)) * 8),
                  Qs + (size_t)(p * 256 + wv * 64) * 8);
    }

    float sum_part[4] = {0.f, 0.f, 0.f, 0.f};
    f32x4 acc_o[4] = {};

    const int lim = qt - 8;        // kt >= lim always included (band)
    int cur = 0;
    while (cur < lim && kmask[cur] == 0ull) ++cur;
    {
        int k0 = cur * 64;
        #pragma unroll
        for (int p = 0; p < 2; ++p) {
            int c = p * 256 + t; int r = c >> 3; int gc = ((c & 7) ^ (r & 7)) * 8;
            gld_lds16(kbase + (size_t)(k0 + r) * DH + gc, Ks[0] + (size_t)(p * 256 + wv * 64) * 8);
            gld_lds16(vbase + (size_t)r * SS + k0 + gc,  Vs[0] + (size_t)(p * 256 + wv * 64) * 8);
        }
    }
    int pb = 0;
    while (cur >= 0) {
        int nxt = cur + 1;
        while (nxt < lim && kmask[nxt] == 0ull) ++nxt;
        if (nxt > qt) nxt = -1;
        __syncthreads();                       // buf pb ready for all waves
        if (nxt >= 0) {
            int k0n = nxt * 64;
            #pragma unroll
            for (int p = 0; p < 2; ++p) {
                int c = p * 256 + t; int r = c >> 3; int gc = ((c & 7) ^ (r & 7)) * 8;
                gld_lds16(kbase + (size_t)(k0n + r) * DH + gc, Ks[pb ^ 1] + (size_t)(p * 256 + wv * 64) * 8);
                gld_lds16(vbase + (size_t)r * SS + k0n + gc,  Vs[pb ^ 1] + (size_t)(p * 256 + wv * 64) * 8);
            }
        }
        const u16* Kt = Ks[pb];
        const u16* Vt = Vs[pb];
        const int k0 = cur * 64;

        f32x4 s_acc[4] = {};
        #pragma unroll
        for (int ks = 0; ks < 2; ++ks) {
            const int arow = wv * 16 + lr;
            bf16x8 af = *(const bf16x8*)&Qs[arow * 64 + (((ks * 4 + lq) ^ (arow & 7)) * 8)];
            #pragma unroll
            for (int ni = 0; ni < 4; ++ni) {
                const int brow = ni * 16 + lr;
                bf16x8 bfr = *(const bf16x8*)&Kt[brow * 64 + (((ks * 4 + lq) ^ (brow & 7)) * 8)];
                s_acc[ni] = __builtin_amdgcn_mfma_f32_16x16x32_bf16(af, bfr, s_acc[ni], 0, 0, 0);
            }
        }
        float sv[4][4];
        if (cur >= qt - 7 && cur != qt) {                    // FULL
            #pragma unroll
            for (int ni = 0; ni < 4; ++ni)
                #pragma unroll
                for (int r = 0; r < 4; ++r) sv[ni][r] = __expf(s_acc[ni][r]);
        } else if (cur == qt) {                              // DIAG
            #pragma unroll
            for (int ni = 0; ni < 4; ++ni) {
                int j = ni * 16 + lr;
                #pragma unroll
                for (int r = 0; r < 4; ++r) {
                    int i = wv * 16 + lq * 4 + r;
                    float p = __expf(s_acc[ni][r]);
                    sv[ni][r] = (j <= i) ? p : 0.f;
                }
            }
        } else {                                             // MASKED
            unsigned long long cm = kmask[cur];
            #pragma unroll
            for (int ni = 0; ni < 4; ++ni) {
                int j = k0 + ni * 16 + lr;
                bool gj = (cm >> (ni * 16 + lr)) & 1ull;
                #pragma unroll
                for (int r = 0; r < 4; ++r) {
                    int i = q0 + wv * 16 + lq * 4 + r;
                    bool ok = ((i - j) < 512) | gj;
                    float p = __expf(s_acc[ni][r]);
                    sv[ni][r] = ok ? p : 0.f;
                }
            }
        }
        #pragma unroll
        for (int ni = 0; ni < 4; ++ni) {
            int col = ni * 16 + lr;
            #pragma unroll
            for (int r = 0; r < 4; ++r) {
                int row = wv * 16 + lq * 4 + r;
                sum_part[r] += sv[ni][r];
                Ps[row * 64 + (((col >> 3) ^ (row & 7)) * 8) + (col & 7)] = f2bf(sv[ni][r]);
            }
        }
        #pragma unroll
        for (int ks = 0; ks < 2; ++ks) {
            const int arow = wv * 16 + lr;
            bf16x8 af = *(const bf16x8*)&Ps[arow * 64 + (((ks * 4 + lq) ^ (arow & 7)) * 8)];
            #pragma unroll
            for (int ni = 0; ni < 4; ++ni) {
                const int brow = ni * 16 + lr;
                bf16x8 bfr = *(const bf16x8*)&Vt[brow * 64 + (((ks * 4 + lq) ^ (brow & 7)) * 8)];
                acc_o[ni] = __builtin_amdgcn_mfma_f32_16x16x32_bf16(af, bfr, acc_o[ni], 0, 0, 0);
            }
        }
        cur = nxt; pb ^= 1;
    }
    float inv_l[4];
    #pragma unroll
    for (int r = 0; r < 4; ++r) {
        float ls = sum_part[r];
        #pragma unroll
        for (int m = 1; m < 16; m <<= 1) ls += __shfl_xor(ls, m, 16);
        inv_l[r] = 1.f / ls;
    }
    u16* obase = ctx + ((size_t)b * SS) * DM + h * DH;
    #pragma unroll
    for (int ni = 0; ni < 4; ++ni)
        #pragma unroll
        for (int r = 0; r < 4; ++r) {
            int i = q0 + wv * 16 + lq * 4 + r;
            obase[(size_t)i * DM + ni * 16 + lr] = f2bf(acc_o[ni][r] * inv_l[r]);
        }
}

// ---------------- Global-row fixup: lane = key, zero in-loop cross-lane ops --
__global__ __launch_bounds__(256) void attn_fix_kernel(const u16* __restrict__ qh,
                                                       const u16* __restrict__ kh,
                                                       const u16* __restrict__ qkv,
                                                       const int* __restrict__ gti,
                                                       u16* __restrict__ ctx) {
    const int gidx = blockIdx.x, bh = blockIdx.y;
    const int b = bh >> 4, h = bh & 15;
    const int t = threadIdx.x, wv = t >> 6, lane = t & 63;
    const int i = gti[gidx];

    __shared__ float qsh[64];
    if (t < 64) qsh[t] = bf2f(qh[((size_t)bh * SS + i) * DH + t]);   // RoPE'd, prescaled
    __syncthreads();
    float qreg[64];
    #pragma unroll
    for (int c = 0; c < 16; ++c) {
        float4 qv = ((const float4*)qsh)[c];   // broadcast
        qreg[c * 4 + 0] = qv.x; qreg[c * 4 + 1] = qv.y;
        qreg[c * 4 + 2] = qv.z; qreg[c * 4 + 3] = qv.w;
    }

    const u16* kb = kh + (size_t)bh * SS * DH;
    const u16* vb = qkv + (size_t)b * SS * 3072 + 2048 + h * DH;

    float Oacc[64];
    #pragma unroll
    for (int d = 0; d < 64; ++d) Oacc[d] = 0.f;
    float lacc = 0.f;

    for (int j0 = wv * 64; j0 <= i; j0 += 256) {
        const int j = j0 + lane;
        const bool valid = (j <= i);
        const int jc = valid ? j : i;
        const s16x8* krow = (const s16x8*)(kb + (size_t)jc * DH);
        float part[8];
        #pragma unroll
        for (int c = 0; c < 8; ++c) {
            s16x8 kv = krow[c];
            float p0 = 0.f;
            #pragma unroll
            for (int e = 0; e < 8; ++e) p0 += qreg[c * 8 + e] * bf2f((u16)kv[e]);
            part[c] = p0;
        }
        float s = ((part[0] + part[1]) + (part[2] + part[3])) +
                  ((part[4] + part[5]) + (part[6] + part[7]));
        const float p = valid ? __expf(s) : 0.f;
        lacc += p;
        const s16x8* vrow = (const s16x8*)(vb + (size_t)jc * 3072);
        #pragma unroll
        for (int c = 0; c < 8; ++c) {
            s16x8 vv = vrow[c];
            #pragma unroll
            for (int e = 0; e < 8; ++e) Oacc[c * 8 + e] += p * bf2f((u16)vv[e]);
        }
    }
    #pragma unroll
    for (int m = 1; m < 64; m <<= 1) {
        lacc += __shfl_xor(lacc, m);
        #pragma unroll
        for (int d = 0; d < 64; ++d) Oacc[d] += __shfl_xor(Oacc[d], m);
    }
    float out = 0.f;
    #pragma unroll
    for (int d = 0; d < 64; ++d) out = (lane == d) ? Oacc[d] : out;
    __shared__ float osum[4][64];
    __shared__ float lsum[4];
    osum[wv][lane] = out;
    if (lane == 0) lsum[wv] = lacc;
    __syncthreads();
    if (wv == 0) {
        float ot = osum[0][lane] + osum[1][lane] + osum[2][lane] + osum[3][lane];
        float lt = lsum[0] + lsum[1] + lsum[2] + lsum[3];
        ctx[((size_t)b * SS + i) * DM + h * DH + lane] = f2bf(ot / lt);
    }
}

extern "C" void kernel_launch(void* const* d_in, const int* in_sizes, int n_in,
                              void* d_out, int out_size, void* d_ws, size_t ws_size,
                              hipStream_t stream) {
    (void)in_sizes; (void)n_in; (void)out_size; (void)ws_size;
    const float* hidden = (const float*)d_in[0];
    const float* ln1_g  = (const float*)d_in[1];
    const float* ln1_b  = (const float*)d_in[2];
    const float* wq = (const float*)d_in[3];  const float* bq = (const float*)d_in[4];
    const float* wk = (const float*)d_in[5];  const float* bk = (const float*)d_in[6];
    const float* wv = (const float*)d_in[7];  const float* bv = (const float*)d_in[8];
    const float* wo = (const float*)d_in[9];  const float* bo = (const float*)d_in[10];
    const float* ln2_g = (const float*)d_in[11];
    const float* ln2_b = (const float*)d_in[12];
    const float* w1 = (const float*)d_in[13]; const float* b1 = (const float*)d_in[14];
    const float* w2 = (const float*)d_in[15]; const float* b2 = (const float*)d_in[16];
    const int*  gti = (const int*)d_in[17];

    char* ws = (char*)d_ws;
    const size_t MB = 1u << 20;
    u16* wqt  = (u16*)(ws + 0 * MB);    // [3072][1024] contiguous (wq|wk|wv transposed)
    u16* wkt  = (u16*)(ws + 2 * MB);
    u16* wvt  = (u16*)(ws + 4 * MB);
    u16* wot  = (u16*)(ws + 6 * MB);
    u16* w1t  = (u16*)(ws + 8 * MB);    // [4096][1024]
    u16* w2t  = (u16*)(ws + 16 * MB);   // [1024][4096]
    u16* xb   = (u16*)(ws + 24 * MB);   // ln1 out; reused as ctx after QKV
    u16* ctx  = xb;
    u16* qkv  = (u16*)(ws + 32 * MB);   // [4096][3072] bf16, 24MB (32..56)
    u16* qhb  = (u16*)(ws + 56 * MB);
    u16* khb  = (u16*)(ws + 64 * MB);
    u16* vtb  = (u16*)(ws + 72 * MB);
    float* hb = (float*)(ws + 80 * MB); // fp32 residual h, 16MB
    u16* act  = (u16*)(ws + 32 * MB);   // 32MB (32..64): qkv+qhb dead after fixup
    u16* yb   = (u16*)(ws + 64 * MB);   // reuses khb (dead after fixup)
    unsigned long long* kmask = (unsigned long long*)(ws + 96 * MB);
    float* bias3 = (float*)(ws + 96 * MB + 8192);

    wtrans4_kernel<<<dim3(16, 16, 4), 256, 0, stream>>>(wq, wk, wv, wo, wqt, wkt, wvt, wot);
    wtrans_kernel<<<dim3(64, 16), 256, 0, stream>>>(w1, w1t, DM, DFF);
    wtrans_kernel<<<dim3(16, 64), 256, 0, stream>>>(w2, w2t, DFF, DM);
    build_aux<<<1, 256, 0, stream>>>(gti, kmask, bq, bk, bv, bias3);

    ln_kernel<false><<<NB * SS, 256, 0, stream>>>(hidden, ln1_g, ln1_b, xb, nullptr, nullptr);

    // fused QKV: A[4096x1024] * [wq|wk|wv]^T -> qkv[4096x3072]
    gemm_bt<0><<<dim3(24, 32), 256, 0, stream>>>(xb, wqt, bias3, nullptr, qkv, NB * SS, 3072, DM, DM);

    rope_kernel<<<(NB * NH * SS * 32) / 256, 256, 0, stream>>>(qkv, qhb, khb);
    vtrans_kernel<<<dim3(SS / 64, NB * NH), 256, 0, stream>>>(qkv, vtb);

    attn_kernel<<<dim3(SS / 64, NB * NH), 256, 0, stream>>>(qhb, khb, vtb, kmask, ctx);
    attn_fix_kernel<<<dim3(8, NB * NH), 256, 0, stream>>>(qhb, khb, qkv, gti, ctx);

    gemm_bt<1><<<dim3(8, 32), 256, 0, stream>>>(ctx, wot, bo, hidden, hb, NB * SS, DM, DM, DM);
    // ln2 + init d_out = h + b2 (accumulation target for split-K w2)
    ln_kernel<true><<<NB * SS, 256, 0, stream>>>(hb, ln2_g, ln2_b, yb, b2, (float*)d_out);
    gemm_bt<2><<<dim3(32, 32), 256, 0, stream>>>(yb, w1t, b1, nullptr, act, NB * SS, DFF, DM, DM);
    // w2 split-K=2 in one dispatch (512 blocks): d_out += act * w2t^T
    gemm_bt<3><<<dim3(8, 32, 2), 256, 0, stream>>>(act, w2t, nullptr, nullptr, d_out, NB * SS, DM, DFF / 2, DFF);
}